// Round 5
// baseline (418.993 us; speedup 1.0000x reference)
//
#include <hip/hip_runtime.h>

#define NN 25000
#define NE 400000
#define CH 128
#define ECH 64
#define KTOT 320     // 2*CH + ECH
#define KPAD 328     // +8 halves pad -> row stride 656B: 2-way bank alias only (free)
#define BE 64        // edges per tile
#define NCHUNK 25    // ceil(NN/1024)
#define NTILE (NE / BE)   // 6250
#define NBP 256      // preprocessing blocks: 1 per CU, guaranteed co-resident

typedef _Float16 half8 __attribute__((ext_vector_type(8)));
typedef _Float16 half4v __attribute__((ext_vector_type(4)));
typedef float f32x4 __attribute__((ext_vector_type(4)));

// software grid barrier (distinct counter per call site, pre-zeroed via hipMemsetAsync)
__device__ inline void gbar(unsigned* c) {
    __syncthreads();
    if (threadIdx.x == 0) {
        __threadfence();
        __hip_atomic_fetch_add(c, 1u, __ATOMIC_ACQ_REL, __HIP_MEMORY_SCOPE_AGENT);
        while (__hip_atomic_load(c, __ATOMIC_ACQUIRE, __HIP_MEMORY_SCOPE_AGENT) < (unsigned)NBP)
            __builtin_amdgcn_s_sleep(2);
        __threadfence();
    }
    __syncthreads();
}

// ---- kernel 1: fused preprocessing (persistent, 256 blocks = 1/CU) ----
__global__ __launch_bounds__(256) void preproc_kernel(
    const float* __restrict__ x, const int* __restrict__ eidx,
    const float* __restrict__ gw, const float* __restrict__ mw,
    float* __restrict__ out, _Float16* __restrict__ xh, _Float16* __restrict__ wp,
    int* __restrict__ cnt, int* __restrict__ cur,
    int* __restrict__ offs, int* __restrict__ tot, int* __restrict__ perm,
    unsigned* __restrict__ bar)
{
    const int tid  = threadIdx.x;
    const int bid  = blockIdx.x;
    const int gtid = bid * 256 + tid;
    const int gsz  = NBP * 256;

    __shared__ int sbuf[256];
    __shared__ int sbase[NCHUNK];

    // Phase A: out = x, xh = fp16(x); pack W; zero cnt+cur
    for (int i = gtid; i < (NN * CH) / 4; i += gsz) {
        float4 v = ((const float4*)x)[i];
        ((float4*)out)[i] = v;
        half4v h;
        h[0] = (_Float16)v.x; h[1] = (_Float16)v.y;
        h[2] = (_Float16)v.z; h[3] = (_Float16)v.w;
        ((half4v*)xh)[i] = h;
    }
    for (int t = gtid; t < 81920; t += gsz) {
        int i    = t & 7;
        int lane = (t >> 3) & 63;
        int ks   = (t >> 9) % 10;
        int gct  = t / 5120;          // 0..15
        int w  = gct >> 2, ct = gct & 3;
        int ch = w * 32 + (ct & 1) * 16 + (lane & 15);
        int k  = ks * 32 + 8 * (lane >> 4) + i;
        const float* src = (ct < 2) ? gw : mw;
        wp[t] = (_Float16)src[ch * KTOT + k];
    }
    for (int i = gtid; i < 50048; i += gsz) cnt[i] = 0;   // cnt + cur contiguous
    gbar(&bar[0]);

    // Phase B: histogram of destination cols
    for (int i = gtid; i < NE; i += gsz) atomicAdd(&cnt[eidx[NE + i]], 1);
    gbar(&bar[1]);

    // Phase C: per-chunk exclusive scan (blocks 0..24 handle 1024 counts each)
    if (bid < NCHUNK) {
        int base = bid * 1024 + tid * 4;
        int v0 = (base + 0 < NN) ? cnt[base + 0] : 0;
        int v1 = (base + 1 < NN) ? cnt[base + 1] : 0;
        int v2 = (base + 2 < NN) ? cnt[base + 2] : 0;
        int v3 = (base + 3 < NN) ? cnt[base + 3] : 0;
        int s = v0 + v1 + v2 + v3;
        sbuf[tid] = s;
        __syncthreads();
        for (int off = 1; off < 256; off <<= 1) {
            int t2 = (tid >= off) ? sbuf[tid - off] : 0;
            __syncthreads();
            sbuf[tid] += t2;
            __syncthreads();
        }
        int excl = sbuf[tid] - s;
        if (base + 0 < NN) { offs[base + 0] = excl; excl += v0; }
        if (base + 1 < NN) { offs[base + 1] = excl; excl += v1; }
        if (base + 2 < NN) { offs[base + 2] = excl; excl += v2; }
        if (base + 3 < NN) { offs[base + 3] = excl; }
        if (tid == 255) tot[bid] = sbuf[255];
    }
    gbar(&bar[2]);

    // Phase D: chunk bases + rank into perm
    if (tid == 0) {
        int a = 0;
        #pragma unroll
        for (int c2 = 0; c2 < NCHUNK; ++c2) { sbase[c2] = a; a += tot[c2]; }
    }
    __syncthreads();
    for (int i = gtid; i < NE; i += gsz) {
        int c = eidx[NE + i];
        int p = offs[c] + sbase[c >> 10] + atomicAdd(&cur[c], 1);
        perm[p] = i;
    }
}

// ---- kernel 2: main fused edge GEMM + activations + segmented scatter (R2-proven) ----
__global__ __launch_bounds__(256) void cgconv_kernel(const _Float16* __restrict__ xh,
                                                     const int* __restrict__ eidx,
                                                     const float* __restrict__ eattr,
                                                     const _Float16* __restrict__ wp,
                                                     const int* __restrict__ perm,
                                                     const float* __restrict__ gate_b,
                                                     const float* __restrict__ msg_b,
                                                     float* __restrict__ out) {
    __shared__ __align__(16) char smem[BE * KPAD * 2];   // 41984 B; aliased Z fp16 / M f32
    __shared__ int rowI[BE];
    __shared__ int colI[BE];
    __shared__ int sI[BE];
    _Float16 (*Z)[KPAD] = (_Float16 (*)[KPAD])smem;
    float* M = (float*)smem;

    int tid = threadIdx.x;
    int e0  = blockIdx.x * BE;    // NE % BE == 0, no tail

    if (tid < BE) {
        int p = perm[e0 + tid];   // sorted-by-col edge ids
        sI[tid]   = p;
        rowI[tid] = eidx[p];
        colI[tid] = eidx[NE + p];
    }
    __syncthreads();

    // stage x[row] -> Z[:, 0:128)
    #pragma unroll
    for (int it = 0; it < 4; ++it) {
        int idx = it * 256 + tid;           // 1024 chunks of 8 halves
        int e = idx >> 4, c = idx & 15;
        int r = rowI[e];
        *(half8*)&Z[e][c * 8] = *(const half8*)&xh[(size_t)r * CH + c * 8];
    }
    // stage x[col] -> Z[:, 128:256)
    #pragma unroll
    for (int it = 0; it < 4; ++it) {
        int idx = it * 256 + tid;
        int e = idx >> 4, c = idx & 15;
        int r = colI[e];
        *(half8*)&Z[e][CH + c * 8] = *(const half8*)&xh[(size_t)r * CH + c * 8];
    }
    // stage edge_attr (fp32 -> fp16) -> Z[:, 256:320)
    #pragma unroll
    for (int it = 0; it < 2; ++it) {
        int idx = it * 256 + tid;           // 512 chunks of 8 floats
        int e = idx >> 3, c = idx & 7;
        const float4* p = (const float4*)&eattr[(size_t)sI[e] * ECH + c * 8];
        float4 v0 = p[0], v1 = p[1];
        half8 h;
        h[0] = (_Float16)v0.x; h[1] = (_Float16)v0.y; h[2] = (_Float16)v0.z; h[3] = (_Float16)v0.w;
        h[4] = (_Float16)v1.x; h[5] = (_Float16)v1.y; h[6] = (_Float16)v1.z; h[7] = (_Float16)v1.w;
        *(half8*)&Z[e][2 * CH + c * 8] = h;
    }
    __syncthreads();

    int lane = tid & 63;
    int w    = tid >> 6;          // wave id: owns channels [32w, 32w+32)
    int l15  = lane & 15;
    int lg   = lane >> 4;

    f32x4 acc[4][4];
    #pragma unroll
    for (int rt = 0; rt < 4; ++rt)
        #pragma unroll
        for (int ct = 0; ct < 4; ++ct) {
            acc[rt][ct][0] = 0.f; acc[rt][ct][1] = 0.f;
            acc[rt][ct][2] = 0.f; acc[rt][ct][3] = 0.f;
        }

    const half8* wpf = (const half8*)wp;
    #pragma unroll
    for (int ks = 0; ks < 10; ++ks) {
        half8 a[4], b[4];
        #pragma unroll
        for (int rt = 0; rt < 4; ++rt)
            a[rt] = *(const half8*)&Z[rt * 16 + l15][ks * 32 + 8 * lg];
        #pragma unroll
        for (int ct = 0; ct < 4; ++ct)
            b[ct] = wpf[(((w * 4 + ct) * 10) + ks) * 64 + lane];
        #pragma unroll
        for (int rt = 0; rt < 4; ++rt)
            #pragma unroll
            for (int ct = 0; ct < 4; ++ct)
                acc[rt][ct] = __builtin_amdgcn_mfma_f32_16x16x32_f16(a[rt], b[ct], acc[rt][ct], 0, 0, 0);
    }

    __syncthreads();   // Z reads done; smem reused as M

    // activations -> M[le][ch] (XOR-swizzled across lg groups)
    #pragma unroll
    for (int ct = 0; ct < 2; ++ct) {
        int ch  = w * 32 + ct * 16 + l15;
        int chs = ch ^ (lg << 3);
        float gb = gate_b[ch];
        float mb = msg_b[ch];
        #pragma unroll
        for (int rt = 0; rt < 4; ++rt) {
            #pragma unroll
            for (int r = 0; r < 4; ++r) {
                int le = rt * 16 + lg * 4 + r;     // C layout: row = 4*lg + reg
                float gv = acc[rt][ct][r] + gb;
                float mv = acc[rt][ct + 2][r] + mb;
                float g  = __builtin_amdgcn_rcpf(1.0f + __expf(-gv));
                float sp = (mv > 15.0f) ? mv : __logf(1.0f + __expf(mv));
                M[le * CH + chs] = g * sp;
            }
        }
    }
    __syncthreads();

    // segmented walk over sorted cols: one atomic per (distinct col, channel)
    int ch2 = tid & 127;
    int h   = tid >> 7;           // two halves of 32 edges
    float a2 = 0.f;
    int prev = colI[h * 32];
    for (int i2 = 0; i2 < 32; ++i2) {
        int e = h * 32 + i2;
        int c = colI[e];
        float m = M[e * CH + (ch2 ^ (((e >> 2) & 3) << 3))];
        if (c != prev) {
            atomicAdd(&out[(size_t)prev * CH + ch2], a2);
            a2 = 0.f;
            prev = c;
        }
        a2 += m;
    }
    atomicAdd(&out[(size_t)prev * CH + ch2], a2);
}

extern "C" void kernel_launch(void* const* d_in, const int* in_sizes, int n_in,
                              void* d_out, int out_size, void* d_ws, size_t ws_size,
                              hipStream_t stream) {
    const float* x      = (const float*)d_in[0];
    const int*   eidx   = (const int*)d_in[1];
    const float* eattr  = (const float*)d_in[2];
    const float* gate_w = (const float*)d_in[3];
    const float* gate_b = (const float*)d_in[4];
    const float* msg_w  = (const float*)d_in[5];
    const float* msg_b  = (const float*)d_in[6];
    float* outp = (float*)d_out;

    char* ws = (char*)d_ws;
    _Float16* xh  = (_Float16*)(ws);                 // 6,400,000 B
    _Float16* wp  = (_Float16*)(ws + 6400000);       //   163,840 B
    int* cnt  = (int*)(ws + 6563840);                //   100,096 B (25024 ints)
    int* cur  = (int*)(ws + 6663936);                //   100,096 B (contiguous after cnt)
    int* offs = (int*)(ws + 6764032);                //   100,096 B
    int* tot  = (int*)(ws + 6864128);                //       128 B
    unsigned* bar = (unsigned*)(ws + 6864256);       //        64 B (3 used)
    int* perm = (int*)(ws + 6864320);                // 1,600,000 B (ends at 8.46 MB)

    hipMemsetAsync(bar, 0, 64, stream);
    preproc_kernel<<<NBP, 256, 0, stream>>>(x, eidx, gate_w, msg_w, outp, xh, wp,
                                            cnt, cur, offs, tot, perm, bar);
    cgconv_kernel<<<NTILE, 256, 0, stream>>>(xh, eidx, eattr, wp, perm, gate_b, msg_b, outp);
}

// Round 6
// 354.048 us; speedup vs baseline: 1.1834x; 1.1834x over previous
//
#include <hip/hip_runtime.h>

#define NN 25000
#define NE 400000
#define CH 128
#define ECH 64
#define KTOT 320          // 2*CH + ECH
#define KP2 264           // phase-A staging width 256 + 8 pad (row 528B: 2-way bank alias, free)
#define BE 64             // edges per tile
#define NTILE (NE / BE)   // 6250

typedef _Float16 half8 __attribute__((ext_vector_type(8)));
typedef _Float16 half4v __attribute__((ext_vector_type(4)));
typedef float f32x4 __attribute__((ext_vector_type(4)));

// ---- k1: out=x copy, xh=fp16(x), pack W, histogram (cnt pre-zeroed by memset) ----
__global__ __launch_bounds__(256) void prep_hist_kernel(
    const float* __restrict__ x, const int* __restrict__ eidx,
    const float* __restrict__ gw, const float* __restrict__ mw,
    float* __restrict__ out, _Float16* __restrict__ xh, _Float16* __restrict__ wp,
    int* __restrict__ cnt)
{
    const int gtid = blockIdx.x * 256 + threadIdx.x;
    const int gsz  = gridDim.x * 256;

    for (int i = gtid; i < (NN * CH) / 4; i += gsz) {     // 800000 float4 units
        float4 v = ((const float4*)x)[i];
        ((float4*)out)[i] = v;
        half4v h;
        h[0] = (_Float16)v.x; h[1] = (_Float16)v.y;
        h[2] = (_Float16)v.z; h[3] = (_Float16)v.w;
        ((half4v*)xh)[i] = h;
    }
    for (int t = gtid; t < 81920; t += gsz) {             // W -> MFMA B-fragment order
        int i    = t & 7;
        int lane = (t >> 3) & 63;
        int ks   = (t >> 9) % 10;
        int gct  = t / 5120;          // 0..15
        int w  = gct >> 2, ct = gct & 3;
        int ch = w * 32 + (ct & 1) * 16 + (lane & 15);
        int k  = ks * 32 + 8 * (lane >> 4) + i;
        const float* src = (ct < 2) ? gw : mw;
        wp[t] = (_Float16)src[ch * KTOT + k];
    }
    for (int i = gtid; i < NE; i += gsz) atomicAdd(&cnt[eidx[NE + i]], 1);
}

// ---- k2: full exclusive scan of 25000 counts in ONE block ----
__global__ __launch_bounds__(1024) void scan_kernel(const int* __restrict__ cnt,
                                                    int* __restrict__ offs) {
    __shared__ int sbuf[1024];
    const int tid = threadIdx.x;
    int vals[25];
    int s = 0;
    if (tid < 1000) {
        #pragma unroll
        for (int j = 0; j < 25; ++j) { vals[j] = cnt[tid * 25 + j]; s += vals[j]; }
    }
    sbuf[tid] = s;
    __syncthreads();
    for (int off = 1; off < 1024; off <<= 1) {
        int t = (tid >= off) ? sbuf[tid - off] : 0;
        __syncthreads();
        sbuf[tid] += t;
        __syncthreads();
    }
    if (tid < 1000) {
        int base = sbuf[tid] - s;     // global exclusive prefix
        #pragma unroll
        for (int j = 0; j < 25; ++j) { offs[tid * 25 + j] = base; base += vals[j]; }
    }
}

// ---- k3: rank edges into perm (+ optionally convert edge_attr -> f16) ----
__global__ __launch_bounds__(256) void rank_eh_kernel(
    const int* __restrict__ eidx, const int* __restrict__ offs,
    int* __restrict__ cur, int* __restrict__ perm,
    const float* __restrict__ eattr, _Float16* __restrict__ eh, int do_eh)
{
    const int gtid = blockIdx.x * 256 + threadIdx.x;
    const int gsz  = gridDim.x * 256;
    for (int i = gtid; i < NE; i += gsz) {
        int c = eidx[NE + i];
        int p = offs[c] + atomicAdd(&cur[c], 1);
        perm[p] = i;
    }
    if (do_eh) {
        for (int u = gtid; u < (NE * ECH) / 8; u += gsz) {   // 3.2M chunks of 8
            const float4* p = (const float4*)&eattr[(size_t)u * 8];
            float4 v0 = p[0], v1 = p[1];
            half8 h;
            h[0] = (_Float16)v0.x; h[1] = (_Float16)v0.y; h[2] = (_Float16)v0.z; h[3] = (_Float16)v0.w;
            h[4] = (_Float16)v1.x; h[5] = (_Float16)v1.y; h[6] = (_Float16)v1.z; h[7] = (_Float16)v1.w;
            ((half8*)eh)[u] = h;
        }
    }
}

// ---- k4: main fused edge GEMM + activations + segmented scatter ----
// Two-phase K staging: phase A = x[row]|x[col] (K 0..255), phase B = eattr (K 256..319)
// reusing the same LDS buffer -> 34.5 KB -> 4 blocks/CU (was 3).
template <int EH16>
__global__ __launch_bounds__(256) void cgconv_kernel(const _Float16* __restrict__ xh,
                                                     const int* __restrict__ eidx,
                                                     const float* __restrict__ eattr,
                                                     const _Float16* __restrict__ eh,
                                                     const _Float16* __restrict__ wp,
                                                     const int* __restrict__ perm,
                                                     const float* __restrict__ gate_b,
                                                     const float* __restrict__ msg_b,
                                                     float* __restrict__ out) {
    __shared__ __align__(16) char smem[BE * KP2 * 2];    // 33792 B; aliased Z fp16 / M f32 (32768)
    __shared__ int rowI[BE];
    __shared__ int colI[BE];
    __shared__ int sI[BE];
    _Float16 (*Z)[KP2] = (_Float16 (*)[KP2])smem;
    float* M = (float*)smem;

    const int tid = threadIdx.x;
    const int e0  = blockIdx.x * BE;   // NE % BE == 0

    if (tid < BE) {
        int p = perm[e0 + tid];        // sorted-by-col edge ids
        sI[tid]   = p;
        rowI[tid] = eidx[p];
        colI[tid] = eidx[NE + p];
    }
    __syncthreads();

    // phase A stage: x[row] -> Z[:,0:128), x[col] -> Z[:,128:256)
    #pragma unroll
    for (int it = 0; it < 4; ++it) {
        int idx = it * 256 + tid;      // 1024 chunks of 8 halves
        int e = idx >> 4, c = idx & 15;
        int r = rowI[e];
        *(half8*)&Z[e][c * 8] = *(const half8*)&xh[(size_t)r * CH + c * 8];
    }
    #pragma unroll
    for (int it = 0; it < 4; ++it) {
        int idx = it * 256 + tid;
        int e = idx >> 4, c = idx & 15;
        int r = colI[e];
        *(half8*)&Z[e][CH + c * 8] = *(const half8*)&xh[(size_t)r * CH + c * 8];
    }
    __syncthreads();

    const int lane = tid & 63;
    const int w    = tid >> 6;         // wave: channels [32w, 32w+32)
    const int l15  = lane & 15;
    const int lg   = lane >> 4;

    f32x4 acc[4][4];
    #pragma unroll
    for (int rt = 0; rt < 4; ++rt)
        #pragma unroll
        for (int ct = 0; ct < 4; ++ct) {
            acc[rt][ct][0] = 0.f; acc[rt][ct][1] = 0.f;
            acc[rt][ct][2] = 0.f; acc[rt][ct][3] = 0.f;
        }

    const half8* wpf = (const half8*)wp;

    // MFMA over phase-A K (ks 0..7)
    #pragma unroll
    for (int ks = 0; ks < 8; ++ks) {
        half8 a[4], b[4];
        #pragma unroll
        for (int rt = 0; rt < 4; ++rt)
            a[rt] = *(const half8*)&Z[rt * 16 + l15][ks * 32 + 8 * lg];
        #pragma unroll
        for (int ct = 0; ct < 4; ++ct)
            b[ct] = wpf[(((w * 4 + ct) * 10) + ks) * 64 + lane];
        #pragma unroll
        for (int rt = 0; rt < 4; ++rt)
            #pragma unroll
            for (int ct = 0; ct < 4; ++ct)
                acc[rt][ct] = __builtin_amdgcn_mfma_f32_16x16x32_f16(a[rt], b[ct], acc[rt][ct], 0, 0, 0);
    }
    __syncthreads();   // phase-A Z reads done

    // phase B stage: edge_attr -> Z[:,0:64)
    #pragma unroll
    for (int it = 0; it < 2; ++it) {
        int idx = it * 256 + tid;      // 512 chunks of 8 halves
        int e = idx >> 3, c = idx & 7;
        half8 h;
        if (EH16) {
            h = *(const half8*)&eh[(size_t)sI[e] * ECH + c * 8];
        } else {
            const float4* p = (const float4*)&eattr[(size_t)sI[e] * ECH + c * 8];
            float4 v0 = p[0], v1 = p[1];
            h[0] = (_Float16)v0.x; h[1] = (_Float16)v0.y; h[2] = (_Float16)v0.z; h[3] = (_Float16)v0.w;
            h[4] = (_Float16)v1.x; h[5] = (_Float16)v1.y; h[6] = (_Float16)v1.z; h[7] = (_Float16)v1.w;
        }
        *(half8*)&Z[e][c * 8] = h;
    }
    __syncthreads();

    // MFMA over phase-B K (ks 8..9)
    #pragma unroll
    for (int ks = 8; ks < 10; ++ks) {
        half8 a[4], b[4];
        #pragma unroll
        for (int rt = 0; rt < 4; ++rt)
            a[rt] = *(const half8*)&Z[rt * 16 + l15][(ks - 8) * 32 + 8 * lg];
        #pragma unroll
        for (int ct = 0; ct < 4; ++ct)
            b[ct] = wpf[(((w * 4 + ct) * 10) + ks) * 64 + lane];
        #pragma unroll
        for (int rt = 0; rt < 4; ++rt)
            #pragma unroll
            for (int ct = 0; ct < 4; ++ct)
                acc[rt][ct] = __builtin_amdgcn_mfma_f32_16x16x32_f16(a[rt], b[ct], acc[rt][ct], 0, 0, 0);
    }
    __syncthreads();   // Z reads done; smem reused as M

    // activations -> M[le][ch] (XOR-swizzled across lg groups)
    #pragma unroll
    for (int ct = 0; ct < 2; ++ct) {
        int ch  = w * 32 + ct * 16 + l15;
        int chs = ch ^ (lg << 3);
        float gb = gate_b[ch];
        float mb = msg_b[ch];
        #pragma unroll
        for (int rt = 0; rt < 4; ++rt) {
            #pragma unroll
            for (int r = 0; r < 4; ++r) {
                int le = rt * 16 + lg * 4 + r;     // C layout: row = 4*lg + reg
                float gv = acc[rt][ct][r] + gb;
                float mv = acc[rt][ct + 2][r] + mb;
                float g  = __builtin_amdgcn_rcpf(1.0f + __expf(-gv));
                float sp = (mv > 15.0f) ? mv : __logf(1.0f + __expf(mv));
                M[le * CH + chs] = g * sp;
            }
        }
    }
    __syncthreads();

    // segmented walk over sorted cols: one atomic per (distinct col, channel)
    int ch2 = tid & 127;
    int h   = tid >> 7;
    float a2 = 0.f;
    int prev = colI[h * 32];
    for (int i2 = 0; i2 < 32; ++i2) {
        int e = h * 32 + i2;
        int c = colI[e];
        float m = M[e * CH + (ch2 ^ (((e >> 2) & 3) << 3))];
        if (c != prev) {
            atomicAdd(&out[(size_t)prev * CH + ch2], a2);
            a2 = 0.f;
            prev = c;
        }
        a2 += m;
    }
    atomicAdd(&out[(size_t)prev * CH + ch2], a2);
}

extern "C" void kernel_launch(void* const* d_in, const int* in_sizes, int n_in,
                              void* d_out, int out_size, void* d_ws, size_t ws_size,
                              hipStream_t stream) {
    const float* x      = (const float*)d_in[0];
    const int*   eidx   = (const int*)d_in[1];
    const float* eattr  = (const float*)d_in[2];
    const float* gate_w = (const float*)d_in[3];
    const float* gate_b = (const float*)d_in[4];
    const float* msg_w  = (const float*)d_in[5];
    const float* msg_b  = (const float*)d_in[6];
    float* outp = (float*)d_out;

    char* ws = (char*)d_ws;
    _Float16* xh  = (_Float16*)(ws);                 // 6,400,000 B
    _Float16* wp  = (_Float16*)(ws + 6400000);       //   163,840 B
    int* cnt  = (int*)(ws + 6563840);                //   100,096 B
    int* cur  = (int*)(ws + 6663936);                //   100,096 B (contiguous after cnt)
    int* offs = (int*)(ws + 6764032);                //   100,096 B
    int* perm = (int*)(ws + 6864128);                // 1,600,000 B (ends 8,464,128)
    _Float16* eh = (_Float16*)(ws + 8464128);        // 51,200,000 B (ends 59,664,128) if it fits
    const int eh16 = (ws_size >= (size_t)59664128) ? 1 : 0;

    hipMemsetAsync(cnt, 0, 200192, stream);          // cnt + cur
    prep_hist_kernel<<<2048, 256, 0, stream>>>(x, eidx, gate_w, msg_w, outp, xh, wp, cnt);
    scan_kernel<<<1, 1024, 0, stream>>>(cnt, offs);
    rank_eh_kernel<<<1024, 256, 0, stream>>>(eidx, offs, cur, perm, eattr, eh, eh16);
    if (eh16)
        cgconv_kernel<1><<<NTILE, 256, 0, stream>>>(xh, eidx, eattr, eh, wp, perm, gate_b, msg_b, outp);
    else
        cgconv_kernel<0><<<NTILE, 256, 0, stream>>>(xh, eidx, eattr, eh, wp, perm, gate_b, msg_b, outp);
}

// Round 7
// 332.594 us; speedup vs baseline: 1.2598x; 1.0645x over previous
//
#include <hip/hip_runtime.h>

#define NN 25000
#define NE 400000
#define CH 128
#define ECH 64
#define KTOT 320          // 2*CH + ECH
#define BE 64             // edges per tile
#define NTILE (NE / BE)   // 6250

typedef _Float16 half8 __attribute__((ext_vector_type(8)));
typedef _Float16 half4v __attribute__((ext_vector_type(4)));
typedef float f32x4 __attribute__((ext_vector_type(4)));
typedef unsigned int u32;

__device__ __forceinline__ void gload16(const void* gsrc, void* ldsdst) {
    __builtin_amdgcn_global_load_lds((const __attribute__((address_space(1))) u32*)gsrc,
                                     (__attribute__((address_space(3))) u32*)ldsdst,
                                     16, 0, 0);
}

// ---- k1: out=x copy, xh=fp16(x), pack W, histogram (cnt pre-zeroed by memset) ----
__global__ __launch_bounds__(256) void prep_hist_kernel(
    const float* __restrict__ x, const int* __restrict__ eidx,
    const float* __restrict__ gw, const float* __restrict__ mw,
    float* __restrict__ out, _Float16* __restrict__ xh, _Float16* __restrict__ wp,
    int* __restrict__ cnt)
{
    const int gtid = blockIdx.x * 256 + threadIdx.x;
    const int gsz  = gridDim.x * 256;

    for (int i = gtid; i < (NN * CH) / 4; i += gsz) {     // 800000 float4 units
        float4 v = ((const float4*)x)[i];
        ((float4*)out)[i] = v;
        half4v h;
        h[0] = (_Float16)v.x; h[1] = (_Float16)v.y;
        h[2] = (_Float16)v.z; h[3] = (_Float16)v.w;
        ((half4v*)xh)[i] = h;
    }
    for (int t = gtid; t < 81920; t += gsz) {             // W -> MFMA B-fragment order
        int i    = t & 7;
        int lane = (t >> 3) & 63;
        int ks   = (t >> 9) % 10;
        int gct  = t / 5120;          // 0..15
        int w  = gct >> 2, ct = gct & 3;
        int ch = w * 32 + (ct & 1) * 16 + (lane & 15);
        int k  = ks * 32 + 8 * (lane >> 4) + i;
        const float* src = (ct < 2) ? gw : mw;
        wp[t] = (_Float16)src[ch * KTOT + k];
    }
    for (int i = gtid; i < NE; i += gsz) atomicAdd(&cnt[eidx[NE + i]], 1);
}

// ---- k2: full exclusive scan of 25000 counts in ONE block ----
__global__ __launch_bounds__(1024) void scan_kernel(const int* __restrict__ cnt,
                                                    int* __restrict__ offs) {
    __shared__ int sbuf[1024];
    const int tid = threadIdx.x;
    int vals[25];
    int s = 0;
    if (tid < 1000) {
        #pragma unroll
        for (int j = 0; j < 25; ++j) { vals[j] = cnt[tid * 25 + j]; s += vals[j]; }
    }
    sbuf[tid] = s;
    __syncthreads();
    for (int off = 1; off < 1024; off <<= 1) {
        int t = (tid >= off) ? sbuf[tid - off] : 0;
        __syncthreads();
        sbuf[tid] += t;
        __syncthreads();
    }
    if (tid < 1000) {
        int base = sbuf[tid] - s;     // global exclusive prefix
        #pragma unroll
        for (int j = 0; j < 25; ++j) { offs[tid * 25 + j] = base; base += vals[j]; }
    }
}

// ---- k3: rank edges; offs is consumed destructively (becomes end-offsets) ----
__global__ __launch_bounds__(256) void rank_kernel(
    const int* __restrict__ eidx, int* __restrict__ offs,
    int* __restrict__ perm, unsigned short* __restrict__ rows16,
    unsigned short* __restrict__ cols16)
{
    const int gtid = blockIdx.x * 256 + threadIdx.x;
    const int gsz  = gridDim.x * 256;
    for (int i = gtid; i < NE; i += gsz) {
        int r = eidx[i];
        int c = eidx[NE + i];
        int p = atomicAdd(&offs[c], 1);
        perm[p]   = i;
        rows16[p] = (unsigned short)r;
        cols16[p] = (unsigned short)c;
    }
}

// ---- k4: main fused edge GEMM + activations + segmented scatter ----
// Phase A: x[row]|x[col] (K 0..255) staged via global_load_lds with XOR-swizzled
//          source (linear LDS dest); reads apply the same swizzle.
// Phase B: eattr f32 loaded to regs EARLY (overlaps staging), converted in-reg,
//          ds_written swizzled into the first 8KB after phase-A MFMA retires.
__global__ __launch_bounds__(256, 4) void cgconv_kernel(
    const _Float16* __restrict__ xh,
    const float* __restrict__ eattr,
    const _Float16* __restrict__ wp,
    const int* __restrict__ perm,
    const unsigned short* __restrict__ rows16,
    const unsigned short* __restrict__ cols16,
    const float* __restrict__ gate_b,
    const float* __restrict__ msg_b,
    float* __restrict__ out)
{
    __shared__ __align__(16) char smem[BE * 256 * 2];   // 32768 B: Z[64][256]f16 / Zb[64][64]f16 / M[64][128]f32
    __shared__ int rowI[BE];
    __shared__ int colI[BE];
    __shared__ int sI[BE];

    const int tid = threadIdx.x;

    // XCD-bijective tile swizzle (nwg=6250: q=781, r=2)
    {
    }
    int orig = blockIdx.x;
    int xcd = orig & 7, j = orig >> 3;
    const int q = NTILE / 8, r = NTILE % 8;
    int tile = (xcd < r ? xcd * (q + 1) : r * (q + 1) + (xcd - r) * q) + j;
    const int e0 = tile * BE;

    if (tid < BE) {
        int g = e0 + tid;
        sI[tid]   = perm[g];
        rowI[tid] = rows16[g];
        colI[tid] = cols16[g];
    }
    __syncthreads();

    const int lane = tid & 63;
    const int w    = tid >> 6;         // wave: channels [32w, 32w+32)
    const int l15  = lane & 15;
    const int lg   = lane >> 4;
    const int wvs  = tid & ~63;        // first tid of this wave

    // ---- phase A staging: 2048 16B chunks via global_load_lds, swizzled source ----
    // LDS slot s holds x-chunk (s&31)^(e&7) of edge e=s>>5; dest linear = smem + s*16.
    #pragma unroll
    for (int it = 0; it < 8; ++it) {
        int s  = it * 256 + wvs + lane;
        int e  = s >> 5, cs = s & 31;
        int cp = cs ^ (e & 7);                    // bits 0-2 xor; bit 3-4 kept
        int rr = (cs < 16) ? rowI[e] : colI[e];
        const _Float16* src = xh + (size_t)rr * CH + (cp & 15) * 8;
        gload16(src, (char*)smem + (size_t)(it * 256 + wvs) * 16);
    }

    // ---- phase B early: eattr f32 -> regs (overlaps phase-A staging latency) ----
    float4 ev[2][2];
    #pragma unroll
    for (int it = 0; it < 2; ++it) {
        int idx = it * 256 + tid;                 // 512 chunks: e = idx>>3, cs = idx&7
        int e = idx >> 3, cs = idx & 7;
        const float4* p = (const float4*)&eattr[(size_t)sI[e] * ECH + cs * 8];
        ev[it][0] = p[0];
        ev[it][1] = p[1];
    }
    __syncthreads();   // drains vmcnt: Z ready (and ev arrived)

    f32x4 acc[4][4];
    #pragma unroll
    for (int rt = 0; rt < 4; ++rt)
        #pragma unroll
        for (int ct = 0; ct < 4; ++ct) {
            acc[rt][ct][0] = 0.f; acc[rt][ct][1] = 0.f;
            acc[rt][ct][2] = 0.f; acc[rt][ct][3] = 0.f;
        }

    const half8* wpf = (const half8*)wp;

    // ---- MFMA over phase-A K (ks 0..7), swizzled reads ----
    #pragma unroll
    for (int ks = 0; ks < 8; ++ks) {
        half8 a[4], b[4];
        #pragma unroll
        for (int rt = 0; rt < 4; ++rt) {
            int R = rt * 16 + l15;
            int slot = (ks * 4 + lg) ^ (l15 & 7);
            a[rt] = *(const half8*)((const char*)smem + (size_t)R * 512 + slot * 16);
        }
        #pragma unroll
        for (int ct = 0; ct < 4; ++ct)
            b[ct] = wpf[(((w * 4 + ct) * 10) + ks) * 64 + lane];
        #pragma unroll
        for (int rt = 0; rt < 4; ++rt)
            #pragma unroll
            for (int ct = 0; ct < 4; ++ct)
                acc[rt][ct] = __builtin_amdgcn_mfma_f32_16x16x32_f16(a[rt], b[ct], acc[rt][ct], 0, 0, 0);
    }
    __syncthreads();   // phase-A Z reads done; first 8KB reusable as Zb

    // ---- phase B: convert + swizzled ds_write into Zb[64][64] (stride 128B) ----
    #pragma unroll
    for (int it = 0; it < 2; ++it) {
        int idx = it * 256 + tid;
        int e = idx >> 3, cs = idx & 7;
        float4 v0 = ev[it][0], v1 = ev[it][1];
        half8 h;
        h[0] = (_Float16)v0.x; h[1] = (_Float16)v0.y; h[2] = (_Float16)v0.z; h[3] = (_Float16)v0.w;
        h[4] = (_Float16)v1.x; h[5] = (_Float16)v1.y; h[6] = (_Float16)v1.z; h[7] = (_Float16)v1.w;
        *(half8*)((char*)smem + (size_t)e * 128 + ((cs ^ (e & 7)) * 16)) = h;
    }
    __syncthreads();

    // ---- MFMA over phase-B K (ks 8..9) ----
    #pragma unroll
    for (int ks = 8; ks < 10; ++ks) {
        half8 a[4], b[4];
        #pragma unroll
        for (int rt = 0; rt < 4; ++rt) {
            int R = rt * 16 + l15;
            int slot = ((ks - 8) * 4 + lg) ^ (l15 & 7);
            a[rt] = *(const half8*)((const char*)smem + (size_t)R * 128 + slot * 16);
        }
        #pragma unroll
        for (int ct = 0; ct < 4; ++ct)
            b[ct] = wpf[(((w * 4 + ct) * 10) + ks) * 64 + lane];
        #pragma unroll
        for (int rt = 0; rt < 4; ++rt)
            #pragma unroll
            for (int ct = 0; ct < 4; ++ct)
                acc[rt][ct] = __builtin_amdgcn_mfma_f32_16x16x32_f16(a[rt], b[ct], acc[rt][ct], 0, 0, 0);
    }
    __syncthreads();   // all Z/Zb reads done; smem reused as M

    // ---- activations -> M[le][ch] (XOR-swizzled across lg groups) ----
    float* M = (float*)smem;
    #pragma unroll
    for (int ct = 0; ct < 2; ++ct) {
        int ch  = w * 32 + ct * 16 + l15;
        int chs = ch ^ (lg << 3);
        float gb = gate_b[ch];
        float mb = msg_b[ch];
        #pragma unroll
        for (int rt = 0; rt < 4; ++rt) {
            #pragma unroll
            for (int rg = 0; rg < 4; ++rg) {
                int le = rt * 16 + lg * 4 + rg;    // C layout: row = 4*lg + reg
                float gv = acc[rt][ct][rg] + gb;
                float mv = acc[rt][ct + 2][rg] + mb;
                float g  = __builtin_amdgcn_rcpf(1.0f + __expf(-gv));
                float sp = (mv > 15.0f) ? mv : __logf(1.0f + __expf(mv));
                M[le * CH + chs] = g * sp;
            }
        }
    }
    __syncthreads();

    // ---- segmented walk over sorted cols: one atomic per (distinct col, channel) ----
    int ch2 = tid & 127;
    int h   = tid >> 7;
    float a2 = 0.f;
    int prev = colI[h * 32];
    for (int i2 = 0; i2 < 32; ++i2) {
        int e = h * 32 + i2;
        int c = colI[e];
        float m = M[e * CH + (ch2 ^ (((e >> 2) & 3) << 3))];
        if (c != prev) {
            atomicAdd(&out[(size_t)prev * CH + ch2], a2);
            a2 = 0.f;
            prev = c;
        }
        a2 += m;
    }
    atomicAdd(&out[(size_t)prev * CH + ch2], a2);
}

extern "C" void kernel_launch(void* const* d_in, const int* in_sizes, int n_in,
                              void* d_out, int out_size, void* d_ws, size_t ws_size,
                              hipStream_t stream) {
    const float* x      = (const float*)d_in[0];
    const int*   eidx   = (const int*)d_in[1];
    const float* eattr  = (const float*)d_in[2];
    const float* gate_w = (const float*)d_in[3];
    const float* gate_b = (const float*)d_in[4];
    const float* msg_w  = (const float*)d_in[5];
    const float* msg_b  = (const float*)d_in[6];
    float* outp = (float*)d_out;

    char* ws = (char*)d_ws;
    _Float16* xh  = (_Float16*)(ws);                       // 6,400,000 B
    _Float16* wp  = (_Float16*)(ws + 6400000);             //   163,840 B
    int* cnt  = (int*)(ws + 6563840);                      //   100,096 B
    int* offs = (int*)(ws + 6663936);                      //   100,096 B
    int* perm = (int*)(ws + 6764032);                      // 1,600,000 B
    unsigned short* rows16 = (unsigned short*)(ws + 8364032);  // 800,000 B
    unsigned short* cols16 = (unsigned short*)(ws + 9164032);  // 800,000 B -> ends 9,964,032

    hipMemsetAsync(cnt, 0, 100096, stream);
    prep_hist_kernel<<<2048, 256, 0, stream>>>(x, eidx, gate_w, msg_w, outp, xh, wp, cnt);
    scan_kernel<<<1, 1024, 0, stream>>>(cnt, offs);
    rank_kernel<<<1024, 256, 0, stream>>>(eidx, offs, perm, rows16, cols16);
    cgconv_kernel<<<NTILE, 256, 0, stream>>>(xh, eattr, wp, perm, rows16, cols16,
                                             gate_b, msg_b, outp);
}